// Round 8
// baseline (261.095 us; speedup 1.0000x reference)
//
#include <hip/hip_runtime.h>

#define Bb 256
#define Nn 240
#define Ee 4338
#define Ff 28
#define Uu 100
#define Kk 128            // U + F
#define Mrows (Bb * Nn)   // 61440
#define ET (Ee + Nn)      // edges incl self-loops
#define AS 136            // LDS A-panel row stride in u16

typedef __attribute__((ext_vector_type(8))) short bf16x8;
typedef __attribute__((ext_vector_type(4))) float f32x4;
typedef unsigned short u16;

__device__ __forceinline__ float bf2f(u16 u) {
  union { unsigned int i; float f; } v; v.i = ((unsigned int)u) << 16; return v.f;
}
__device__ __forceinline__ u16 f2bf(float f) {
  union { float ff; unsigned int i; } v; v.ff = f;
  unsigned int x = v.i;
  return (u16)((x + 0x7fffu + ((x >> 16) & 1u)) >> 16);
}
__device__ __forceinline__ void split4(const float4 v, ushort4& h, ushort4& l) {
  u16 h0 = f2bf(v.x), h1 = f2bf(v.y), h2 = f2bf(v.z), h3 = f2bf(v.w);
  h.x = h0; h.y = h1; h.z = h2; h.w = h3;
  l.x = f2bf(v.x - bf2f(h0)); l.y = f2bf(v.y - bf2f(h1));
  l.z = f2bf(v.z - bf2f(h2)); l.w = f2bf(v.w - bf2f(h3));
}

// ---------------------------------------------------------------------------
// k_init: blocks 0..31 = weight prep (fp32 -> padded/transposed bf16 hi/lo);
// block 32 = dst-grouped CSR. Merged to save one launch gap (r17).
// ---------------------------------------------------------------------------
__global__ __launch_bounds__(256) void k_init(
    const float* __restrict__ Wg, const float* __restrict__ Wru, const float* __restrict__ Wc,
    u16* __restrict__ wgh, u16* __restrict__ wgl,
    u16* __restrict__ wruh, u16* __restrict__ wrul,
    u16* __restrict__ wch, u16* __restrict__ wcl,
    const int* __restrict__ esrc, const int* __restrict__ edst,
    int* __restrict__ coff, int* __restrict__ cslot) {
  int tid = threadIdx.x;
  if (blockIdx.x < 32) {
    int gt = blockIdx.x * 256 + tid, GS = 32 * 256;
    for (int i = gt; i < 128 * Kk; i += GS) {
      int c = i >> 7, k = i & 127;
      float v = (c < Uu) ? Wg[c * Kk + k] : 0.f;
      u16 h = f2bf(v); wgh[i] = h; wgl[i] = f2bf(v - bf2f(h));
    }
    for (int i = gt; i < 256 * Kk; i += GS) {
      int n = i >> 7, kp = i & 127;
      int k = (kp < Uu) ? (kp + Ff) : (kp - Uu);
      float v = (n < 2 * Uu) ? Wru[k * (2 * Uu) + n] : 0.f;
      u16 h = f2bf(v); wruh[i] = h; wrul[i] = f2bf(v - bf2f(h));
    }
    for (int i = gt; i < 128 * Kk; i += GS) {
      int n = i >> 7, kp = i & 127;
      int k = (kp < Uu) ? (kp + Ff) : (kp - Uu);
      float v = (n < Uu) ? Wc[k * Uu + n] : 0.f;
      u16 h = f2bf(v); wch[i] = h; wcl[i] = f2bf(v - bf2f(h));
    }
  } else {
    __shared__ int cnt[256];
    __shared__ int scan[256];
    __shared__ int cur[Nn];
    cnt[tid] = 0;
    __syncthreads();
    for (int e = tid; e < Ee; e += 256) atomicAdd(&cnt[edst[e]], 1);
    __syncthreads();
    int x = (tid < Nn) ? (cnt[tid] + 1) : 0;   // +1 = self-loop slot
    int incl = x;
    scan[tid] = incl;
    __syncthreads();
#pragma unroll
    for (int d = 1; d < 256; d <<= 1) {
      int t = (tid >= d) ? scan[tid - d] : 0;
      __syncthreads();
      incl += t;
      scan[tid] = incl;
      __syncthreads();
    }
    int excl = incl - x;
    if (tid < Nn) { coff[tid] = excl; cur[tid] = excl; }
    if (tid == 0) coff[Nn] = scan[Nn - 1];
    __syncthreads();
    for (int e = tid; e < Ee; e += 256) {
      int d = edst[e];
      cslot[atomicAdd(&cur[d], 1)] = esrc[e];
    }
    for (int n = tid; n < Nn; n += 256) cslot[atomicAdd(&cur[n], 1)] = n;
  }
}

// ---------------------------------------------------------------------------
// k_fused: ONE BLOCK PER SAMPLE (256 blocks, 1 blk/CU, ~154 KB LDS), 1024 thr
// (16 waves = 4/SIMD). Wave w owns (tile = w&7, rt0 = w>>3).
// r17: the 64-VGPR budget for 1024-thr blocks is immovable (r13/r15/r16 all
// pinned at 64) -> fit UNDER it. GRU weight frags are no longer held in 96
// persistent VGPRs; they are reloaded per chunk per k-slice through asm-
// laundered pointers (defeats LICM re-hoisting). ru pass 0/1 merged into one
// k-loop sharing the a/bb LDS reads (per-accumulator MFMA order unchanged ->
// bit-identical). Max live regs ~60 < 64 -> no spill; reloads are L2-resident.
// ---------------------------------------------------------------------------
__global__ __launch_bounds__(1024, 1) void k_fused(
    const float* __restrict__ stt, const float* __restrict__ inp,
    const u16* __restrict__ wgh, const u16* __restrict__ wgl,
    const float* __restrict__ att_s, const float* __restrict__ att_d,
    const int* __restrict__ coff, const int* __restrict__ cslot,
    const float* __restrict__ gbias, const float* __restrict__ b1,
    const u16* __restrict__ wruh, const u16* __restrict__ wrul,
    const float* __restrict__ bru,
    const u16* __restrict__ wch, const u16* __restrict__ wcl,
    const float* __restrict__ bc,
    float* __restrict__ out) {
  __shared__ float hbuf[Nn * Uu];      // 96,000 B : h (fp32), full sample
  __shared__ u16 ahL[32 * AS];         //  8,704 B : A-panel hi
  __shared__ u16 alL[32 * AS];         //  8,704 B : A-panel lo
  __shared__ float gch[32 * Uu];       // 12,800 B : gstate chunk (fp32)
  __shared__ u16 ugQ[32 * Uu];         //  6,400 B : u-gate chunk (u16 fixpt)
  __shared__ float asrcL[Nn];          //    960 B
  __shared__ float adstL[Nn];          //    960 B
  __shared__ int coffL[Nn + 1];        //    964 B
  __shared__ int cslotL[ET];           // 18,312 B  -> total ~153.8 KB

  int tid = threadIdx.x;
  int b = blockIdx.x;
  const size_t sbase = (size_t)b * Nn * Uu;
  const size_t ibase = (size_t)b * Nn * Ff;

  // ---- init: CSR to LDS, zero att accumulators ----
  for (int i = tid; i < Nn + 1; i += 1024) coffL[i] = coff[i];
  for (int i = tid; i < ET; i += 1024) cslotL[i] = cslot[i];
  for (int i = tid; i < Nn; i += 1024) { asrcL[i] = 0.f; adstL[i] = 0.f; }

  int w = tid >> 6, l = tid & 63, l15 = l & 15, q = l >> 4;
  int tile = w & 7, rt0 = w >> 3;      // wave's output tile and row-half
  int cw = tile * 16 + l15;            // this wave's output column
  int llb = l & 31, half = l >> 5;

  f32x4 zero = {0.f, 0.f, 0.f, 0.f};

  // ================= phase A: h = x @ Wg^T, att dots =================
  {
    bf16x8 wh[4], wl[4];
#pragma unroll
    for (int s = 0; s < 4; ++s) {
      const int o = cw * Kk + s * 32 + q * 8;
      wh[s] = *(const bf16x8*)(wgh + o);
      wl[s] = *(const bf16x8*)(wgl + o);
    }
    float av = (cw < Uu) ? att_s[cw] : 0.f;
    float dv = (cw < Uu) ? att_d[cw] : 0.f;

    for (int ch0 = 0; ch0 < Nn; ch0 += 32) {
      int rows = Nn - ch0; if (rows > 32) rows = 32;
      bool actrt = (rt0 * 16 < rows);
      for (int j = tid; j < rows * 32; j += 1024) {
        int r = j >> 5, g = j & 31;
        float4 v = (g < 25)
            ? *(const float4*)(stt + sbase + (size_t)(ch0 + r) * Uu + g * 4)
            : *(const float4*)(inp + ibase + (size_t)(ch0 + r) * Ff + (g - 25) * 4);
        ushort4 hh, lo;
        split4(v, hh, lo);
        *(ushort4*)(ahL + r * AS + g * 4) = hh;
        *(ushort4*)(alL + r * AS + g * 4) = lo;
      }
      __syncthreads();
      f32x4 acc = zero;
      if (actrt) {
#pragma unroll
        for (int s = 0; s < 4; ++s) {
          bf16x8 a = *(const bf16x8*)(ahL + (rt0 * 16 + l15) * AS + s * 32 + q * 8);
          bf16x8 bb = *(const bf16x8*)(alL + (rt0 * 16 + l15) * AS + s * 32 + q * 8);
          acc = __builtin_amdgcn_mfma_f32_16x16x32_bf16(a, wh[s], acc, 0, 0, 0);
          acc = __builtin_amdgcn_mfma_f32_16x16x32_bf16(bb, wh[s], acc, 0, 0, 0);
          acc = __builtin_amdgcn_mfma_f32_16x16x32_bf16(a, wl[s], acc, 0, 0, 0);
        }
#pragma unroll
        for (int i = 0; i < 4; ++i) {
          float v = acc[i];
          int row = rt0 * 16 + q * 4 + i;
          if (cw < Uu) hbuf[(ch0 + row) * Uu + cw] = v;
          float va = v * av, vd = v * dv;
#pragma unroll
          for (int msk = 1; msk < 16; msk <<= 1) {
            va += __shfl_xor(va, msk, 64);
            vd += __shfl_xor(vd, msk, 64);
          }
          if (l15 == 0) {
            atomicAdd(&asrcL[ch0 + row], va);
            atomicAdd(&adstL[ch0 + row], vd);
          }
        }
      }
      __syncthreads();
    }
  }

  // ---- per-wave scalars (small, cheap to keep live) ----
  int cw1 = 128 + cw;                  // ru pass-1 column
  float bru0 = bru[cw];
  float bru1 = (cw1 < 2 * Uu) ? bru[cw1] : 0.f;
  float bcv = (cw < Uu) ? bc[cw] : 0.f;
  float4 gbv = {0.f, 0.f, 0.f, 0.f};   // gat_bias + bias1, lanes 0..24
  if (l < 25) {
    int u0 = l * 4;
    gbv.x = gbias[u0 + 0] + b1[u0 + 0];
    gbv.y = gbias[u0 + 1] + b1[u0 + 1];
    gbv.z = gbias[u0 + 2] + b1[u0 + 2];
    gbv.w = gbias[u0 + 3] + b1[u0 + 3];
  }

  // ============ phase B+C per 32-row chunk: attention then GRU ============
  for (int ch0 = 0; ch0 < Nn; ch0 += 32) {
    int rows = Nn - ch0; if (rows > 32) rows = 32;
    bool actrt = (rt0 * 16 < rows);

    // ---- B: attention for dst nodes [ch0, ch0+rows), spread over 16 waves --
    for (int n = ch0 + w; n < ch0 + rows; n += 16) {
      int o0 = coffL[n], deg = coffL[n + 1] - o0;
      float ad = adstL[n];
      float ax = 0.f, ay = 0.f, az = 0.f, aw2 = 0.f, den = 0.f;
      for (int c0 = 0; c0 < deg; c0 += 64) {
        int e = c0 + l;
        float we = 0.f; int s = 0;
        if (e < deg) {
          s = cslotL[o0 + e];
          float sc = asrcL[s] + ad;
          sc = (sc > 0.f) ? sc : 0.2f * sc;
          we = __expf(sc);
        }
        float d = we;
#pragma unroll
        for (int msk = 1; msk < 64; msk <<= 1) d += __shfl_xor(d, msk, 64);
        den += d;
        int cn = deg - c0; if (cn > 64) cn = 64;
        for (int e2 = 0; e2 < cn; e2 += 2) {
          int eh = e2 + half;
          float w2 = __shfl(we, eh, 64);
          int s2 = __shfl(s, eh, 64);
          if ((llb < 25) && eh < cn) {
            const float4 hv = *(const float4*)(hbuf + s2 * Uu + llb * 4);
            ax += w2 * hv.x; ay += w2 * hv.y; az += w2 * hv.z; aw2 += w2 * hv.w;
          }
        }
      }
      ax += __shfl_xor(ax, 32, 64);
      ay += __shfl_xor(ay, 32, 64);
      az += __shfl_xor(az, 32, 64);
      aw2 += __shfl_xor(aw2, 32, 64);
      if (l < 25) {
        float inv = 1.f / den;
        float4 o;
        o.x = ax * inv + gbv.x;
        o.y = ay * inv + gbv.y;
        o.z = az * inv + gbv.z;
        o.w = aw2 * inv + gbv.w;
        *(float4*)(gch + (n - ch0) * Uu + l * 4) = o;
      }
    }
    __syncthreads();   // gch complete; all waves past previous chunk's C

    // ---- C: GRU for rows [ch0, ch0+rows) ----
    for (int j = tid; j < rows * 32; j += 1024) {
      int r = j >> 5, g = j & 31;
      float4 v = (g < 25)
          ? *(const float4*)(gch + r * Uu + g * 4)
          : *(const float4*)(inp + ibase + (size_t)(ch0 + r) * Ff + (g - 25) * 4);
      ushort4 hh, lo;
      split4(v, hh, lo);
      *(ushort4*)(ahL + r * AS + g * 4) = hh;
      *(ushort4*)(alL + r * AS + g * 4) = lo;
    }
    float sv[4];
    if (actrt) {
#pragma unroll
      for (int i = 0; i < 4; ++i) {
        int row = rt0 * 16 + q * 4 + i;
        sv[i] = (cw < Uu) ? gch[row * Uu + cw] : 0.f;
      }
    }
    __syncthreads();   // staging + sv reads of gch done

    // launder weight pointers EACH chunk so frag loads stay in the loop body
    // (transient ~16 regs per k-slice) instead of 96 persistent regs (spill).
    const u16* wruhc = wruh; const u16* wrulc = wrul;
    asm volatile("" : "+s"(wruhc), "+s"(wrulc));

    float pr[4];
    // ru passes 0+1 merged: one k-loop, shared a/bb reads, two accumulators.
    if (actrt) {
      f32x4 acc = zero, acc1 = zero;
#pragma unroll
      for (int s = 0; s < 4; ++s) {
        const int ar = (rt0 * 16 + l15) * AS + s * 32 + q * 8;
        bf16x8 a = *(const bf16x8*)(ahL + ar);
        bf16x8 bb = *(const bf16x8*)(alL + ar);
        const int o0 = cw * Kk + s * 32 + q * 8;
        const int o1 = cw1 * Kk + s * 32 + q * 8;
        bf16x8 wh0 = *(const bf16x8*)(wruhc + o0);
        bf16x8 wl0 = *(const bf16x8*)(wrulc + o0);
        bf16x8 wh1 = *(const bf16x8*)(wruhc + o1);
        bf16x8 wl1 = *(const bf16x8*)(wrulc + o1);
        acc = __builtin_amdgcn_mfma_f32_16x16x32_bf16(a, wh0, acc, 0, 0, 0);
        acc = __builtin_amdgcn_mfma_f32_16x16x32_bf16(bb, wh0, acc, 0, 0, 0);
        acc = __builtin_amdgcn_mfma_f32_16x16x32_bf16(a, wl0, acc, 0, 0, 0);
        acc1 = __builtin_amdgcn_mfma_f32_16x16x32_bf16(a, wh1, acc1, 0, 0, 0);
        acc1 = __builtin_amdgcn_mfma_f32_16x16x32_bf16(bb, wh1, acc1, 0, 0, 0);
        acc1 = __builtin_amdgcn_mfma_f32_16x16x32_bf16(a, wl1, acc1, 0, 0, 0);
      }
#pragma unroll
      for (int i = 0; i < 4; ++i) {
        int row = rt0 * 16 + q * 4 + i;
        float y = acc[i] + bru0;
        float g = 1.f / (1.f + __expf(-y));
        if (cw < Uu) pr[i] = g * sv[i];
        else ugQ[row * Uu + (cw - Uu)] = (u16)(g * 65535.f + 0.5f);
        float y1 = acc1[i] + bru1;
        float g1 = 1.f / (1.f + __expf(-y1));
        if (cw1 < 2 * Uu) ugQ[row * Uu + (cw1 - Uu)] = (u16)(g1 * 65535.f + 0.5f);
      }
    }
    __syncthreads();   // all ru LDS reads + ugQ writes complete

    // substitute r*st into A-panel cols < 100
    if (actrt) {
#pragma unroll
      for (int i = 0; i < 4; ++i) {
        int row = rt0 * 16 + q * 4 + i;
        if (cw < Uu) {
          float p = pr[i];
          u16 hh = f2bf(p);
          ahL[row * AS + cw] = hh;
          alL[row * AS + cw] = f2bf(p - bf2f(hh));
        }
      }
    }
    __syncthreads();   // cat2 = [r*st | xi] ready

    // c GEMM + blend, cols cw (laundered per-chunk weight reload)
    const u16* wchc = wch; const u16* wclc = wcl;
    asm volatile("" : "+s"(wchc), "+s"(wclc));
    if (actrt) {
      f32x4 acc = zero;
#pragma unroll
      for (int s = 0; s < 4; ++s) {
        const int ar = (rt0 * 16 + l15) * AS + s * 32 + q * 8;
        bf16x8 a = *(const bf16x8*)(ahL + ar);
        bf16x8 bb = *(const bf16x8*)(alL + ar);
        const int o0 = cw * Kk + s * 32 + q * 8;
        bf16x8 ch_ = *(const bf16x8*)(wchc + o0);
        bf16x8 cl_ = *(const bf16x8*)(wclc + o0);
        acc = __builtin_amdgcn_mfma_f32_16x16x32_bf16(a, ch_, acc, 0, 0, 0);
        acc = __builtin_amdgcn_mfma_f32_16x16x32_bf16(bb, ch_, acc, 0, 0, 0);
        acc = __builtin_amdgcn_mfma_f32_16x16x32_bf16(a, cl_, acc, 0, 0, 0);
      }
#pragma unroll
      for (int i = 0; i < 4; ++i) {
        int row = rt0 * 16 + q * 4 + i;
        if (cw < Uu) {
          float y = acc[i] + bcv;
          float cv = 1.f - 2.f / (__expf(2.f * y) + 1.f);
          float u = (float)ugQ[row * Uu + cw] * (1.f / 65535.f);
          out[sbase + (size_t)(ch0 + row) * Uu + cw] = u * sv[i] + (1.f - u) * cv;
        }
      }
    }
    // no trailing barrier needed: next chunk's B only writes gch (readers all
    // passed the post-staging sync) and the post-B sync orders ahL reuse.
  }
}

// ---------------------------------------------------------------------------
extern "C" void kernel_launch(void* const* d_in, const int* in_sizes, int n_in,
                              void* d_out, int out_size, void* d_ws, size_t ws_size,
                              hipStream_t stream) {
  const float* inp   = (const float*)d_in[0];
  const float* stt   = (const float*)d_in[1];
  const int*   esrc  = (const int*)d_in[2];
  const int*   edst  = (const int*)d_in[3];
  const float* Wg    = (const float*)d_in[4];
  const float* att_s = (const float*)d_in[5];
  const float* att_d = (const float*)d_in[6];
  const float* gbias = (const float*)d_in[7];
  const float* b1    = (const float*)d_in[8];
  const float* Wru   = (const float*)d_in[9];
  const float* bru   = (const float*)d_in[10];
  const float* Wc    = (const float*)d_in[11];
  const float* bc    = (const float*)d_in[12];
  float* out = (float*)d_out;

  char* base = (char*)d_ws;
  size_t o = 0;
  auto alloc = [&](size_t bytes) -> void* {
    void* p = base + o;
    o = (o + bytes + 255) & ~(size_t)255;
    return p;
  };
  u16* wgh  = (u16*)alloc(128 * Kk * sizeof(u16));
  u16* wgl  = (u16*)alloc(128 * Kk * sizeof(u16));
  u16* wruh = (u16*)alloc(256 * Kk * sizeof(u16));
  u16* wrul = (u16*)alloc(256 * Kk * sizeof(u16));
  u16* wch  = (u16*)alloc(128 * Kk * sizeof(u16));
  u16* wcl  = (u16*)alloc(128 * Kk * sizeof(u16));
  int* coff  = (int*)alloc((Nn + 1) * sizeof(int));
  int* cslot = (int*)alloc(ET * sizeof(int));

  k_init<<<33, 256, 0, stream>>>(Wg, Wru, Wc, wgh, wgl, wruh, wrul, wch, wcl,
                                 esrc, edst, coff, cslot);
  k_fused<<<Bb, 1024, 0, stream>>>(stt, inp, wgh, wgl, att_s, att_d, coff, cslot,
                                   gbias, b1, wruh, wrul, bru, wch, wcl, bc, out);
}

// Round 10
// 220.131 us; speedup vs baseline: 1.1861x; 1.1861x over previous
//
#include <hip/hip_runtime.h>

#define Bb 256
#define Nn 240
#define Ee 4338
#define Ff 28
#define Uu 100
#define Kk 128            // U + F
#define ET (Ee + Nn)      // edges incl self-loops
#define AS 136            // LDS A-panel row stride in u16

typedef __attribute__((ext_vector_type(8))) short bf16x8;
typedef __attribute__((ext_vector_type(4))) float f32x4;
typedef unsigned short u16;

__device__ __forceinline__ float bf2f(u16 u) {
  union { unsigned int i; float f; } v; v.i = ((unsigned int)u) << 16; return v.f;
}
__device__ __forceinline__ u16 f2bf(float f) {
  union { float ff; unsigned int i; } v; v.ff = f;
  unsigned int x = v.i;
  return (u16)((x + 0x7fffu + ((x >> 16) & 1u)) >> 16);
}
__device__ __forceinline__ void split4(const float4 v, ushort4& h, ushort4& l) {
  u16 h0 = f2bf(v.x), h1 = f2bf(v.y), h2 = f2bf(v.z), h3 = f2bf(v.w);
  h.x = h0; h.y = h1; h.z = h2; h.w = h3;
  l.x = f2bf(v.x - bf2f(h0)); l.y = f2bf(v.y - bf2f(h1));
  l.z = f2bf(v.z - bf2f(h2)); l.w = f2bf(v.w - bf2f(h3));
}
__device__ __forceinline__ bf16x8 pack8(ushort4 a, ushort4 b) {
  bf16x8 r;
  r[0] = (short)a.x; r[1] = (short)a.y; r[2] = (short)a.z; r[3] = (short)a.w;
  r[4] = (short)b.x; r[5] = (short)b.y; r[6] = (short)b.z; r[7] = (short)b.w;
  return r;
}

// ---------------------------------------------------------------------------
// k_fused: ONE LAUNCH, ONE BLOCK PER SAMPLE (256 blocks, 512 thr, 8 waves,
// ~156 KB LDS, 1 blk/CU). Structure = r12 (proven 134 us config: weights held
// in regs, VGPR 108 under the (512,2) 128-reg budget).
// r18/r19: k_init ELIMINATED (totals-vs-dispatch arithmetic across r12/r16/
// r17 shows a constant ~95 us outside k_fused). Each block builds the CSR in
// LDS (histogram+scan+scatter; same nondeterministic-order class that passed
// all session) and converts fp32 weights -> bf16 hi/lo fragments in-register
// with IDENTICAL f2bf/split math (bit-identical values). r19 = r18 re-run
// (infra failure, kernel audited clean) minus the redundant cntL buffer.
// ---------------------------------------------------------------------------
__global__ __launch_bounds__(512, 2) void k_fused(
    const float* __restrict__ stt, const float* __restrict__ inp,
    const float* __restrict__ Wg,
    const float* __restrict__ att_s, const float* __restrict__ att_d,
    const int* __restrict__ esrc, const int* __restrict__ edst,
    const float* __restrict__ gbias, const float* __restrict__ b1,
    const float* __restrict__ Wru, const float* __restrict__ bru,
    const float* __restrict__ Wc, const float* __restrict__ bc,
    float* __restrict__ out) {
  __shared__ float hbuf[Nn * Uu];      // 96,000 B : h (fp32), full sample
  __shared__ u16 ahL[32 * AS];         //  8,704 B : A-panel hi
  __shared__ u16 alL[32 * AS];         //  8,704 B : A-panel lo
  __shared__ float gch[32 * Uu];       // 12,800 B : gstate chunk (fp32)
  __shared__ u16 ugQ[32 * Uu];         //  6,400 B : u-gate chunk (u16 fixpt)
  __shared__ float asrcL[Nn];          //    960 B
  __shared__ float adstL[Nn];          //    960 B
  __shared__ int coffL[Nn + 1];        //    964 B
  __shared__ int cslotL[ET];           // 18,312 B
  __shared__ int curL[Nn];             //    960 B (CSR build)
  __shared__ int scanA[256];           //  1,024 B (CSR hist+scan) ~155.8 KB

  int tid = threadIdx.x;
  int b = blockIdx.x;
  const size_t sbase = (size_t)b * Nn * Uu;
  const size_t ibase = (size_t)b * Nn * Ff;

  // ================= in-block CSR build + att-accum zero =================
  if (tid < 256) scanA[tid] = 0;       // histogram buffer (low Nn slots used)
  for (int i = tid; i < Nn; i += 512) { asrcL[i] = 0.f; adstL[i] = 0.f; }
  __syncthreads();
  for (int e = tid; e < Ee; e += 512) atomicAdd(&scanA[edst[e]], 1);
  __syncthreads();
  int xv = 0, incl = 0;
  if (tid < 256) {
    xv = (tid < Nn) ? (scanA[tid] + 1) : 0;   // +1 = self-loop slot
    incl = xv;
  }
  __syncthreads();                     // all histogram reads done
  if (tid < 256) scanA[tid] = incl;
  __syncthreads();
#pragma unroll
  for (int d = 1; d < 256; d <<= 1) {
    int t = 0;
    if (tid < 256 && tid >= d) t = scanA[tid - d];
    __syncthreads();
    if (tid < 256) { incl += t; scanA[tid] = incl; }
    __syncthreads();
  }
  if (tid < 256) {
    int excl = incl - xv;
    if (tid < Nn) { coffL[tid] = excl; curL[tid] = excl; }
    if (tid == 0) coffL[Nn] = scanA[Nn - 1];
  }
  __syncthreads();
  for (int e = tid; e < Ee; e += 512) {
    int d = edst[e];
    cslotL[atomicAdd(&curL[d], 1)] = esrc[e];
  }
  for (int n = tid; n < Nn; n += 512) cslotL[atomicAdd(&curL[n], 1)] = n;
  // cslotL/coffL complete before phase B (phase A's barriers intervene).

  int w = tid >> 6, l = tid & 63, l15 = l & 15, q = l >> 4;
  int cw = w * 16 + l15;               // this wave's output column (tile = w)
  int llb = l & 31, half = l >> 5;

  float4 gbv = {0.f, 0.f, 0.f, 0.f};   // gat_bias + bias1, lanes 0..24
  if (l < 25) {
    int u0 = l * 4;
    gbv.x = gbias[u0 + 0] + b1[u0 + 0];
    gbv.y = gbias[u0 + 1] + b1[u0 + 1];
    gbv.z = gbias[u0 + 2] + b1[u0 + 2];
    gbv.w = gbias[u0 + 3] + b1[u0 + 3];
  }

  f32x4 zero = {0.f, 0.f, 0.f, 0.f};

  // ================= phase A: h = x @ Wg^T, att dots =================
  {
    // in-register Wg conversion (contiguous float4 loads; identical split math)
    bf16x8 wh[4], wl[4];
#pragma unroll
    for (int s = 0; s < 4; ++s) {
      float4 v0 = {0.f, 0.f, 0.f, 0.f}, v1 = {0.f, 0.f, 0.f, 0.f};
      if (cw < Uu) {
        v0 = *(const float4*)(Wg + cw * Kk + s * 32 + q * 8);
        v1 = *(const float4*)(Wg + cw * Kk + s * 32 + q * 8 + 4);
      }
      ushort4 h0, l0, h1, l1;
      split4(v0, h0, l0);
      split4(v1, h1, l1);
      wh[s] = pack8(h0, h1);
      wl[s] = pack8(l0, l1);
    }
    float av = (cw < Uu) ? att_s[cw] : 0.f;
    float dv = (cw < Uu) ? att_d[cw] : 0.f;

    for (int ch0 = 0; ch0 < Nn; ch0 += 32) {
      int rows = Nn - ch0; if (rows > 32) rows = 32;
      int nrt = rows >> 4;
      for (int j = tid; j < rows * 32; j += 512) {
        int r = j >> 5, g = j & 31;
        float4 v = (g < 25)
            ? *(const float4*)(stt + sbase + (size_t)(ch0 + r) * Uu + g * 4)
            : *(const float4*)(inp + ibase + (size_t)(ch0 + r) * Ff + (g - 25) * 4);
        ushort4 hh, lo;
        split4(v, hh, lo);
        *(ushort4*)(ahL + r * AS + g * 4) = hh;
        *(ushort4*)(alL + r * AS + g * 4) = lo;
      }
      __syncthreads();
      f32x4 acc[2]; acc[0] = zero; acc[1] = zero;
#pragma unroll
      for (int rt = 0; rt < 2; ++rt) if (rt < nrt) {
#pragma unroll
        for (int s = 0; s < 4; ++s) {
          bf16x8 a = *(const bf16x8*)(ahL + (rt * 16 + l15) * AS + s * 32 + q * 8);
          bf16x8 bb = *(const bf16x8*)(alL + (rt * 16 + l15) * AS + s * 32 + q * 8);
          acc[rt] = __builtin_amdgcn_mfma_f32_16x16x32_bf16(a, wh[s], acc[rt], 0, 0, 0);
          acc[rt] = __builtin_amdgcn_mfma_f32_16x16x32_bf16(bb, wh[s], acc[rt], 0, 0, 0);
          acc[rt] = __builtin_amdgcn_mfma_f32_16x16x32_bf16(a, wl[s], acc[rt], 0, 0, 0);
        }
      }
#pragma unroll
      for (int rt = 0; rt < 2; ++rt) if (rt < nrt) {
#pragma unroll
        for (int i = 0; i < 4; ++i) {
          float v = acc[rt][i];
          int row = rt * 16 + q * 4 + i;
          if (cw < Uu) hbuf[(ch0 + row) * Uu + cw] = v;
          float va = v * av, vd = v * dv;
#pragma unroll
          for (int msk = 1; msk < 16; msk <<= 1) {
            va += __shfl_xor(va, msk, 64);
            vd += __shfl_xor(vd, msk, 64);
          }
          if (l15 == 0) {
            atomicAdd(&asrcL[ch0 + row], va);
            atomicAdd(&adstL[ch0 + row], vd);
          }
        }
      }
      __syncthreads();
    }
  }

  // ---- GRU weight fragments: in-register fp32 gather + convert, held ----
  bf16x8 r0h[4], r0l[4], r1h[4], r1l[4], cch[4], ccl[4];
  int cw1 = 128 + cw;                  // ru pass-1 column
#pragma unroll
  for (int s = 0; s < 4; ++s) {
    int kb = s * 32 + q * 8;
#pragma unroll
    for (int j = 0; j < 8; ++j) {
      int kp = kb + j;
      int k = (kp < Uu) ? (kp + Ff) : (kp - Uu);
      float v0 = Wru[k * (2 * Uu) + cw];                       // cw<128<200
      u16 h0 = f2bf(v0);
      r0h[s][j] = (short)h0; r0l[s][j] = (short)f2bf(v0 - bf2f(h0));
      float v1 = (cw1 < 2 * Uu) ? Wru[k * (2 * Uu) + cw1] : 0.f;
      u16 h1 = f2bf(v1);
      r1h[s][j] = (short)h1; r1l[s][j] = (short)f2bf(v1 - bf2f(h1));
      float v2 = (cw < Uu) ? Wc[k * Uu + cw] : 0.f;
      u16 h2 = f2bf(v2);
      cch[s][j] = (short)h2; ccl[s][j] = (short)f2bf(v2 - bf2f(h2));
    }
  }
  float bru0 = bru[cw];
  float bru1 = (cw1 < 2 * Uu) ? bru[cw1] : 0.f;
  float bcv = (cw < Uu) ? bc[cw] : 0.f;

  // ============ phase B+C per 32-row chunk: attention then GRU ============
  for (int ch0 = 0; ch0 < Nn; ch0 += 32) {
    int rows = Nn - ch0; if (rows > 32) rows = 32;
    int nrt = rows >> 4;

    // ---- B: attention for dst nodes [ch0, ch0+rows), one dst per wave ----
    for (int n = ch0 + w; n < ch0 + rows; n += 8) {
      int o0 = coffL[n], deg = coffL[n + 1] - o0;
      float ad = adstL[n];
      float ax = 0.f, ay = 0.f, az = 0.f, aw2 = 0.f, den = 0.f;
      for (int c0 = 0; c0 < deg; c0 += 64) {
        int e = c0 + l;
        float we = 0.f; int s = 0;
        if (e < deg) {
          s = cslotL[o0 + e];
          float sc = asrcL[s] + ad;
          sc = (sc > 0.f) ? sc : 0.2f * sc;
          we = __expf(sc);
        }
        float d = we;
#pragma unroll
        for (int msk = 1; msk < 64; msk <<= 1) d += __shfl_xor(d, msk, 64);
        den += d;
        int cn = deg - c0; if (cn > 64) cn = 64;
        for (int e2 = 0; e2 < cn; e2 += 2) {
          int eh = e2 + half;
          float w2 = __shfl(we, eh, 64);
          int s2 = __shfl(s, eh, 64);
          if ((llb < 25) && eh < cn) {
            const float4 hv = *(const float4*)(hbuf + s2 * Uu + llb * 4);
            ax += w2 * hv.x; ay += w2 * hv.y; az += w2 * hv.z; aw2 += w2 * hv.w;
          }
        }
      }
      ax += __shfl_xor(ax, 32, 64);
      ay += __shfl_xor(ay, 32, 64);
      az += __shfl_xor(az, 32, 64);
      aw2 += __shfl_xor(aw2, 32, 64);
      if (l < 25) {
        float inv = 1.f / den;
        float4 o;
        o.x = ax * inv + gbv.x;
        o.y = ay * inv + gbv.y;
        o.z = az * inv + gbv.z;
        o.w = aw2 * inv + gbv.w;
        *(float4*)(gch + (n - ch0) * Uu + l * 4) = o;
      }
    }
    __syncthreads();   // gch complete; all waves past previous chunk's C

    // ---- C: GRU for rows [ch0, ch0+rows) ----
    for (int j = tid; j < rows * 32; j += 512) {
      int r = j >> 5, g = j & 31;
      float4 v = (g < 25)
          ? *(const float4*)(gch + r * Uu + g * 4)
          : *(const float4*)(inp + ibase + (size_t)(ch0 + r) * Ff + (g - 25) * 4);
      ushort4 hh, lo;
      split4(v, hh, lo);
      *(ushort4*)(ahL + r * AS + g * 4) = hh;
      *(ushort4*)(alL + r * AS + g * 4) = lo;
    }
    float sv[2][4];
#pragma unroll
    for (int rt = 0; rt < 2; ++rt) if (rt < nrt) {
#pragma unroll
      for (int i = 0; i < 4; ++i) {
        int row = rt * 16 + q * 4 + i;
        sv[rt][i] = (cw < Uu) ? gch[row * Uu + cw] : 0.f;
      }
    }
    __syncthreads();   // staging + sv reads of gch done

    float pr[2][4];
    // ru pass 0: cols cw -> r-gate (c<100) + u-gate (100..127)
    {
      f32x4 acc[2]; acc[0] = zero; acc[1] = zero;
#pragma unroll
      for (int rt = 0; rt < 2; ++rt) if (rt < nrt) {
#pragma unroll
        for (int s = 0; s < 4; ++s) {
          bf16x8 a = *(const bf16x8*)(ahL + (rt * 16 + l15) * AS + s * 32 + q * 8);
          bf16x8 bb = *(const bf16x8*)(alL + (rt * 16 + l15) * AS + s * 32 + q * 8);
          acc[rt] = __builtin_amdgcn_mfma_f32_16x16x32_bf16(a, r0h[s], acc[rt], 0, 0, 0);
          acc[rt] = __builtin_amdgcn_mfma_f32_16x16x32_bf16(bb, r0h[s], acc[rt], 0, 0, 0);
          acc[rt] = __builtin_amdgcn_mfma_f32_16x16x32_bf16(a, r0l[s], acc[rt], 0, 0, 0);
        }
      }
#pragma unroll
      for (int rt = 0; rt < 2; ++rt) if (rt < nrt) {
#pragma unroll
        for (int i = 0; i < 4; ++i) {
          int row = rt * 16 + q * 4 + i;
          float y = acc[rt][i] + bru0;
          float g = 1.f / (1.f + __expf(-y));
          if (cw < Uu) pr[rt][i] = g * sv[rt][i];
          else ugQ[row * Uu + (cw - Uu)] = (u16)(g * 65535.f + 0.5f);
        }
      }
    }
    // ru pass 1: cols cw1 in [128,256) -> u-gate (128..199)
    {
      f32x4 acc[2]; acc[0] = zero; acc[1] = zero;
#pragma unroll
      for (int rt = 0; rt < 2; ++rt) if (rt < nrt) {
#pragma unroll
        for (int s = 0; s < 4; ++s) {
          bf16x8 a = *(const bf16x8*)(ahL + (rt * 16 + l15) * AS + s * 32 + q * 8);
          bf16x8 bb = *(const bf16x8*)(alL + (rt * 16 + l15) * AS + s * 32 + q * 8);
          acc[rt] = __builtin_amdgcn_mfma_f32_16x16x32_bf16(a, r1h[s], acc[rt], 0, 0, 0);
          acc[rt] = __builtin_amdgcn_mfma_f32_16x16x32_bf16(bb, r1h[s], acc[rt], 0, 0, 0);
          acc[rt] = __builtin_amdgcn_mfma_f32_16x16x32_bf16(a, r1l[s], acc[rt], 0, 0, 0);
        }
      }
#pragma unroll
      for (int rt = 0; rt < 2; ++rt) if (rt < nrt) {
#pragma unroll
        for (int i = 0; i < 4; ++i) {
          int row = rt * 16 + q * 4 + i;
          float y = acc[rt][i] + bru1;
          float g = 1.f / (1.f + __expf(-y));
          if (cw1 < 2 * Uu) ugQ[row * Uu + (cw1 - Uu)] = (u16)(g * 65535.f + 0.5f);
        }
      }
    }
    __syncthreads();   // all ru LDS reads + ugQ writes complete

    // substitute r*st into A-panel cols < 100
#pragma unroll
    for (int rt = 0; rt < 2; ++rt) if (rt < nrt) {
#pragma unroll
      for (int i = 0; i < 4; ++i) {
        int row = rt * 16 + q * 4 + i;
        if (cw < Uu) {
          float p = pr[rt][i];
          u16 hh = f2bf(p);
          ahL[row * AS + cw] = hh;
          alL[row * AS + cw] = f2bf(p - bf2f(hh));
        }
      }
    }
    __syncthreads();   // cat2 = [r*st | xi] ready

    // c GEMM + blend, cols cw
    {
      f32x4 acc[2]; acc[0] = zero; acc[1] = zero;
#pragma unroll
      for (int rt = 0; rt < 2; ++rt) if (rt < nrt) {
#pragma unroll
        for (int s = 0; s < 4; ++s) {
          bf16x8 a = *(const bf16x8*)(ahL + (rt * 16 + l15) * AS + s * 32 + q * 8);
          bf16x8 bb = *(const bf16x8*)(alL + (rt * 16 + l15) * AS + s * 32 + q * 8);
          acc[rt] = __builtin_amdgcn_mfma_f32_16x16x32_bf16(a, cch[s], acc[rt], 0, 0, 0);
          acc[rt] = __builtin_amdgcn_mfma_f32_16x16x32_bf16(bb, cch[s], acc[rt], 0, 0, 0);
          acc[rt] = __builtin_amdgcn_mfma_f32_16x16x32_bf16(a, ccl[s], acc[rt], 0, 0, 0);
        }
      }
#pragma unroll
      for (int rt = 0; rt < 2; ++rt) if (rt < nrt) {
#pragma unroll
        for (int i = 0; i < 4; ++i) {
          int row = rt * 16 + q * 4 + i;
          if (cw < Uu) {
            float y = acc[rt][i] + bcv;
            float cv = 1.f - 2.f / (__expf(2.f * y) + 1.f);
            float u = (float)ugQ[row * Uu + cw] * (1.f / 65535.f);
            out[sbase + (size_t)(ch0 + row) * Uu + cw] = u * sv[rt][i] + (1.f - u) * cv;
          }
        }
      }
    }
    // no trailing barrier needed: next chunk's B only writes gch (readers all
    // passed the post-staging sync) and the post-B sync orders ahL reuse.
  }
}

// ---------------------------------------------------------------------------
extern "C" void kernel_launch(void* const* d_in, const int* in_sizes, int n_in,
                              void* d_out, int out_size, void* d_ws, size_t ws_size,
                              hipStream_t stream) {
  const float* inp   = (const float*)d_in[0];
  const float* stt   = (const float*)d_in[1];
  const int*   esrc  = (const int*)d_in[2];
  const int*   edst  = (const int*)d_in[3];
  const float* Wg    = (const float*)d_in[4];
  const float* att_s = (const float*)d_in[5];
  const float* att_d = (const float*)d_in[6];
  const float* gbias = (const float*)d_in[7];
  const float* b1    = (const float*)d_in[8];
  const float* Wru   = (const float*)d_in[9];
  const float* bru   = (const float*)d_in[10];
  const float* Wc    = (const float*)d_in[11];
  const float* bc    = (const float*)d_in[12];
  float* out = (float*)d_out;

  k_fused<<<Bb, 512, 0, stream>>>(stt, inp, Wg, att_s, att_d, esrc, edst,
                                  gbias, b1, Wru, bru, Wc, bc, out);
}

// Round 11
// 217.978 us; speedup vs baseline: 1.1978x; 1.0099x over previous
//
#include <hip/hip_runtime.h>

#define Bb 256
#define Nn 240
#define Ee 4338
#define Ff 28
#define Uu 100
#define Kk 128            // U + F
#define ET (Ee + Nn)      // edges incl self-loops
#define AS 136            // LDS A-panel row stride in u16

typedef __attribute__((ext_vector_type(8))) short bf16x8;
typedef __attribute__((ext_vector_type(4))) float f32x4;
typedef unsigned short u16;

__device__ __forceinline__ float bf2f(u16 u) {
  union { unsigned int i; float f; } v; v.i = ((unsigned int)u) << 16; return v.f;
}
__device__ __forceinline__ u16 f2bf(float f) {
  union { float ff; unsigned int i; } v; v.ff = f;
  unsigned int x = v.i;
  return (u16)((x + 0x7fffu + ((x >> 16) & 1u)) >> 16);
}
__device__ __forceinline__ void split4(const float4 v, ushort4& h, ushort4& l) {
  u16 h0 = f2bf(v.x), h1 = f2bf(v.y), h2 = f2bf(v.z), h3 = f2bf(v.w);
  h.x = h0; h.y = h1; h.z = h2; h.w = h3;
  l.x = f2bf(v.x - bf2f(h0)); l.y = f2bf(v.y - bf2f(h1));
  l.z = f2bf(v.z - bf2f(h2)); l.w = f2bf(v.w - bf2f(h3));
}
__device__ __forceinline__ bf16x8 pack8(ushort4 a, ushort4 b) {
  bf16x8 r;
  r[0] = (short)a.x; r[1] = (short)a.y; r[2] = (short)a.z; r[3] = (short)a.w;
  r[4] = (short)b.x; r[5] = (short)b.y; r[6] = (short)b.z; r[7] = (short)b.w;
  return r;
}

// ---------------------------------------------------------------------------
// k_fused: ONE LAUNCH, ONE BLOCK PER SAMPLE (256 blocks, 512 thr, 8 waves,
// ~156 KB LDS, 1 blk/CU). r19 measured: 167.8 us kernel, 120 VGPR, no spill.
// r20: init overlap. The CSR build's ~22 block barriers (hist+Hillis-Steele
// scan+scatter) were serial overhead at 1 blk/CU. Now: histogram overlaps the
// Wg register conversion; the scan is a ZERO-BARRIER single-wave shfl scan on
// wave 0 running CONCURRENTLY with waves 1-7 staging phase-A chunk 0; scatter
// folds into the first MFMA segment. Init barriers 22 -> 3. Phase A is
// stage-ahead (same 2 barriers/chunk). GEMM/attention math byte-identical.
// ---------------------------------------------------------------------------
__global__ __launch_bounds__(512, 2) void k_fused(
    const float* __restrict__ stt, const float* __restrict__ inp,
    const float* __restrict__ Wg,
    const float* __restrict__ att_s, const float* __restrict__ att_d,
    const int* __restrict__ esrc, const int* __restrict__ edst,
    const float* __restrict__ gbias, const float* __restrict__ b1,
    const float* __restrict__ Wru, const float* __restrict__ bru,
    const float* __restrict__ Wc, const float* __restrict__ bc,
    float* __restrict__ out) {
  __shared__ float hbuf[Nn * Uu];      // 96,000 B : h (fp32), full sample
  __shared__ u16 ahL[32 * AS];         //  8,704 B : A-panel hi
  __shared__ u16 alL[32 * AS];         //  8,704 B : A-panel lo
  __shared__ float gch[32 * Uu];       // 12,800 B : gstate chunk (fp32)
  __shared__ u16 ugQ[32 * Uu];         //  6,400 B : u-gate chunk (u16 fixpt)
  __shared__ float asrcL[Nn];          //    960 B
  __shared__ float adstL[Nn];          //    960 B
  __shared__ int coffL[Nn + 1];        //    964 B
  __shared__ int cslotL[ET];           // 18,312 B
  __shared__ int curL[Nn];             //    960 B (CSR build)
  __shared__ int cntA[Nn];             //    960 B (CSR histogram)

  int tid = threadIdx.x;
  int b = blockIdx.x;
  const size_t sbase = (size_t)b * Nn * Uu;
  const size_t ibase = (size_t)b * Nn * Ff;

  int w = tid >> 6, l = tid & 63, l15 = l & 15, q = l >> 4;
  int cw = w * 16 + l15;               // this wave's output column (tile = w)
  int llb = l & 31, half = l >> 5;

  f32x4 zero = {0.f, 0.f, 0.f, 0.f};

  // staging helper: rows [c0, c0+rowsn) of [st|xi] -> ahL/alL split-bf16
  auto stageChunk = [&](int c0, int rowsn, int base, int stride) {
    for (int j = base; j < rowsn * 32; j += stride) {
      int r = j >> 5, g = j & 31;
      float4 v = (g < 25)
          ? *(const float4*)(stt + sbase + (size_t)(c0 + r) * Uu + g * 4)
          : *(const float4*)(inp + ibase + (size_t)(c0 + r) * Ff + (g - 25) * 4);
      ushort4 hh, lo;
      split4(v, hh, lo);
      *(ushort4*)(ahL + r * AS + g * 4) = hh;
      *(ushort4*)(alL + r * AS + g * 4) = lo;
    }
  };

  // ================= init (overlapped) + phase A =================
  {
    // -- zero counters --
    for (int i = tid; i < Nn; i += 512) { cntA[i] = 0; asrcL[i] = 0.f; adstL[i] = 0.f; }
    __syncthreads();

    // -- histogram (LDS atomics) overlapped with Wg register conversion --
    for (int e = tid; e < Ee; e += 512) atomicAdd(&cntA[edst[e]], 1);
    bf16x8 wh[4], wl[4];
#pragma unroll
    for (int s = 0; s < 4; ++s) {
      float4 v0 = {0.f, 0.f, 0.f, 0.f}, v1 = {0.f, 0.f, 0.f, 0.f};
      if (cw < Uu) {
        v0 = *(const float4*)(Wg + cw * Kk + s * 32 + q * 8);
        v1 = *(const float4*)(Wg + cw * Kk + s * 32 + q * 8 + 4);
      }
      ushort4 h0, l0, h1, l1;
      split4(v0, h0, l0);
      split4(v1, h1, l1);
      wh[s] = pack8(h0, h1);
      wl[s] = pack8(l0, l1);
    }
    float av = (cw < Uu) ? att_s[cw] : 0.f;
    float dv = (cw < Uu) ? att_d[cw] : 0.f;
    __syncthreads();                   // histogram complete

    // -- wave 0: zero-barrier shfl scan  ||  waves 1-7: stage chunk 0 --
    if (w == 0) {
      int carry = 0;
#pragma unroll
      for (int seg = 0; seg < 4; ++seg) {
        int idx = seg * 64 + l;
        int x = (idx < Nn) ? (cntA[idx] + 1) : 0;   // +1 = self-loop slot
        int v = x;
#pragma unroll
        for (int d = 1; d < 64; d <<= 1) {
          int t = __shfl_up(v, d, 64);
          if (l >= d) v += t;
        }
        if (idx < Nn) {
          int excl = carry + v - x;
          coffL[idx] = excl;
          curL[idx] = excl;
        }
        carry += __shfl(v, 63, 64);
      }
      if (l == 0) coffL[Nn] = carry;
    } else {
      stageChunk(0, 32, tid - 64, 448);
    }
    __syncthreads();                   // scan + chunk-0 staging complete

    // -- scatter (folds into first MFMA segment) --
    for (int e = tid; e < Ee; e += 512) {
      int d = edst[e];
      cslotL[atomicAdd(&curL[d], 1)] = esrc[e];
    }
    for (int n = tid; n < Nn; n += 512) cslotL[atomicAdd(&curL[n], 1)] = n;

    // -- phase A chunks (stage-ahead; 2 barriers/chunk as before) --
    for (int ch0 = 0; ch0 < Nn; ch0 += 32) {
      int rows = Nn - ch0; if (rows > 32) rows = 32;
      int nrt = rows >> 4;
      f32x4 acc[2]; acc[0] = zero; acc[1] = zero;
#pragma unroll
      for (int rt = 0; rt < 2; ++rt) if (rt < nrt) {
#pragma unroll
        for (int s = 0; s < 4; ++s) {
          bf16x8 a = *(const bf16x8*)(ahL + (rt * 16 + l15) * AS + s * 32 + q * 8);
          bf16x8 bb = *(const bf16x8*)(alL + (rt * 16 + l15) * AS + s * 32 + q * 8);
          acc[rt] = __builtin_amdgcn_mfma_f32_16x16x32_bf16(a, wh[s], acc[rt], 0, 0, 0);
          acc[rt] = __builtin_amdgcn_mfma_f32_16x16x32_bf16(bb, wh[s], acc[rt], 0, 0, 0);
          acc[rt] = __builtin_amdgcn_mfma_f32_16x16x32_bf16(a, wl[s], acc[rt], 0, 0, 0);
        }
      }
#pragma unroll
      for (int rt = 0; rt < 2; ++rt) if (rt < nrt) {
#pragma unroll
        for (int i = 0; i < 4; ++i) {
          float v = acc[rt][i];
          int row = rt * 16 + q * 4 + i;
          if (cw < Uu) hbuf[(ch0 + row) * Uu + cw] = v;
          float va = v * av, vd = v * dv;
#pragma unroll
          for (int msk = 1; msk < 16; msk <<= 1) {
            va += __shfl_xor(va, msk, 64);
            vd += __shfl_xor(vd, msk, 64);
          }
          if (l15 == 0) {
            atomicAdd(&asrcL[ch0 + row], va);
            atomicAdd(&adstL[ch0 + row], vd);
          }
        }
      }
      __syncthreads();                 // MFMA reads of ahL/alL done
      int nx = ch0 + 32;
      if (nx < Nn) {
        int rowsn = Nn - nx; if (rowsn > 32) rowsn = 32;
        stageChunk(nx, rowsn, tid, 512);
      }
      __syncthreads();                 // next chunk staged
    }
  }

  float4 gbv = {0.f, 0.f, 0.f, 0.f};   // gat_bias + bias1, lanes 0..24
  if (l < 25) {
    int u0 = l * 4;
    gbv.x = gbias[u0 + 0] + b1[u0 + 0];
    gbv.y = gbias[u0 + 1] + b1[u0 + 1];
    gbv.z = gbias[u0 + 2] + b1[u0 + 2];
    gbv.w = gbias[u0 + 3] + b1[u0 + 3];
  }

  // ---- GRU weight fragments: in-register fp32 gather + convert, held ----
  bf16x8 r0h[4], r0l[4], r1h[4], r1l[4], cch[4], ccl[4];
  int cw1 = 128 + cw;                  // ru pass-1 column
#pragma unroll
  for (int s = 0; s < 4; ++s) {
    int kb = s * 32 + q * 8;
#pragma unroll
    for (int j = 0; j < 8; ++j) {
      int kp = kb + j;
      int k = (kp < Uu) ? (kp + Ff) : (kp - Uu);
      float v0 = Wru[k * (2 * Uu) + cw];                       // cw<128<200
      u16 h0 = f2bf(v0);
      r0h[s][j] = (short)h0; r0l[s][j] = (short)f2bf(v0 - bf2f(h0));
      float v1 = (cw1 < 2 * Uu) ? Wru[k * (2 * Uu) + cw1] : 0.f;
      u16 h1 = f2bf(v1);
      r1h[s][j] = (short)h1; r1l[s][j] = (short)f2bf(v1 - bf2f(h1));
      float v2 = (cw < Uu) ? Wc[k * Uu + cw] : 0.f;
      u16 h2 = f2bf(v2);
      cch[s][j] = (short)h2; ccl[s][j] = (short)f2bf(v2 - bf2f(h2));
    }
  }
  float bru0 = bru[cw];
  float bru1 = (cw1 < 2 * Uu) ? bru[cw1] : 0.f;
  float bcv = (cw < Uu) ? bc[cw] : 0.f;

  // ============ phase B+C per 32-row chunk: attention then GRU ============
  for (int ch0 = 0; ch0 < Nn; ch0 += 32) {
    int rows = Nn - ch0; if (rows > 32) rows = 32;
    int nrt = rows >> 4;

    // ---- B: attention for dst nodes [ch0, ch0+rows), one dst per wave ----
    for (int n = ch0 + w; n < ch0 + rows; n += 8) {
      int o0 = coffL[n], deg = coffL[n + 1] - o0;
      float ad = adstL[n];
      float ax = 0.f, ay = 0.f, az = 0.f, aw2 = 0.f, den = 0.f;
      for (int c0 = 0; c0 < deg; c0 += 64) {
        int e = c0 + l;
        float we = 0.f; int s = 0;
        if (e < deg) {
          s = cslotL[o0 + e];
          float sc = asrcL[s] + ad;
          sc = (sc > 0.f) ? sc : 0.2f * sc;
          we = __expf(sc);
        }
        float d = we;
#pragma unroll
        for (int msk = 1; msk < 64; msk <<= 1) d += __shfl_xor(d, msk, 64);
        den += d;
        int cn = deg - c0; if (cn > 64) cn = 64;
        for (int e2 = 0; e2 < cn; e2 += 2) {
          int eh = e2 + half;
          float w2 = __shfl(we, eh, 64);
          int s2 = __shfl(s, eh, 64);
          if ((llb < 25) && eh < cn) {
            const float4 hv = *(const float4*)(hbuf + s2 * Uu + llb * 4);
            ax += w2 * hv.x; ay += w2 * hv.y; az += w2 * hv.z; aw2 += w2 * hv.w;
          }
        }
      }
      ax += __shfl_xor(ax, 32, 64);
      ay += __shfl_xor(ay, 32, 64);
      az += __shfl_xor(az, 32, 64);
      aw2 += __shfl_xor(aw2, 32, 64);
      if (l < 25) {
        float inv = 1.f / den;
        float4 o;
        o.x = ax * inv + gbv.x;
        o.y = ay * inv + gbv.y;
        o.z = az * inv + gbv.z;
        o.w = aw2 * inv + gbv.w;
        *(float4*)(gch + (n - ch0) * Uu + l * 4) = o;
      }
    }
    __syncthreads();   // gch complete; all waves past previous chunk's C

    // ---- C: GRU for rows [ch0, ch0+rows) ----
    for (int j = tid; j < rows * 32; j += 512) {
      int r = j >> 5, g = j & 31;
      float4 v = (g < 25)
          ? *(const float4*)(gch + r * Uu + g * 4)
          : *(const float4*)(inp + ibase + (size_t)(ch0 + r) * Ff + (g - 25) * 4);
      ushort4 hh, lo;
      split4(v, hh, lo);
      *(ushort4*)(ahL + r * AS + g * 4) = hh;
      *(ushort4*)(alL + r * AS + g * 4) = lo;
    }
    float sv[2][4];
#pragma unroll
    for (int rt = 0; rt < 2; ++rt) if (rt < nrt) {
#pragma unroll
      for (int i = 0; i < 4; ++i) {
        int row = rt * 16 + q * 4 + i;
        sv[rt][i] = (cw < Uu) ? gch[row * Uu + cw] : 0.f;
      }
    }
    __syncthreads();   // staging + sv reads of gch done

    float pr[2][4];
    // ru pass 0: cols cw -> r-gate (c<100) + u-gate (100..127)
    {
      f32x4 acc[2]; acc[0] = zero; acc[1] = zero;
#pragma unroll
      for (int rt = 0; rt < 2; ++rt) if (rt < nrt) {
#pragma unroll
        for (int s = 0; s < 4; ++s) {
          bf16x8 a = *(const bf16x8*)(ahL + (rt * 16 + l15) * AS + s * 32 + q * 8);
          bf16x8 bb = *(const bf16x8*)(alL + (rt * 16 + l15) * AS + s * 32 + q * 8);
          acc[rt] = __builtin_amdgcn_mfma_f32_16x16x32_bf16(a, r0h[s], acc[rt], 0, 0, 0);
          acc[rt] = __builtin_amdgcn_mfma_f32_16x16x32_bf16(bb, r0h[s], acc[rt], 0, 0, 0);
          acc[rt] = __builtin_amdgcn_mfma_f32_16x16x32_bf16(a, r0l[s], acc[rt], 0, 0, 0);
        }
      }
#pragma unroll
      for (int rt = 0; rt < 2; ++rt) if (rt < nrt) {
#pragma unroll
        for (int i = 0; i < 4; ++i) {
          int row = rt * 16 + q * 4 + i;
          float y = acc[rt][i] + bru0;
          float g = 1.f / (1.f + __expf(-y));
          if (cw < Uu) pr[rt][i] = g * sv[rt][i];
          else ugQ[row * Uu + (cw - Uu)] = (u16)(g * 65535.f + 0.5f);
        }
      }
    }
    // ru pass 1: cols cw1 in [128,256) -> u-gate (128..199)
    {
      f32x4 acc[2]; acc[0] = zero; acc[1] = zero;
#pragma unroll
      for (int rt = 0; rt < 2; ++rt) if (rt < nrt) {
#pragma unroll
        for (int s = 0; s < 4; ++s) {
          bf16x8 a = *(const bf16x8*)(ahL + (rt * 16 + l15) * AS + s * 32 + q * 8);
          bf16x8 bb = *(const bf16x8*)(alL + (rt * 16 + l15) * AS + s * 32 + q * 8);
          acc[rt] = __builtin_amdgcn_mfma_f32_16x16x32_bf16(a, r1h[s], acc[rt], 0, 0, 0);
          acc[rt] = __builtin_amdgcn_mfma_f32_16x16x32_bf16(bb, r1h[s], acc[rt], 0, 0, 0);
          acc[rt] = __builtin_amdgcn_mfma_f32_16x16x32_bf16(a, r1l[s], acc[rt], 0, 0, 0);
        }
      }
#pragma unroll
      for (int rt = 0; rt < 2; ++rt) if (rt < nrt) {
#pragma unroll
        for (int i = 0; i < 4; ++i) {
          int row = rt * 16 + q * 4 + i;
          float y = acc[rt][i] + bru1;
          float g = 1.f / (1.f + __expf(-y));
          if (cw1 < 2 * Uu) ugQ[row * Uu + (cw1 - Uu)] = (u16)(g * 65535.f + 0.5f);
        }
      }
    }
    __syncthreads();   // all ru LDS reads + ugQ writes complete

    // substitute r*st into A-panel cols < 100
#pragma unroll
    for (int rt = 0; rt < 2; ++rt) if (rt < nrt) {
#pragma unroll
      for (int i = 0; i < 4; ++i) {
        int row = rt * 16 + q * 4 + i;
        if (cw < Uu) {
          float p = pr[rt][i];
          u16 hh = f2bf(p);
          ahL[row * AS + cw] = hh;
          alL[row * AS + cw] = f2bf(p - bf2f(hh));
        }
      }
    }
    __syncthreads();   // cat2 = [r*st | xi] ready

    // c GEMM + blend, cols cw
    {
      f32x4 acc[2]; acc[0] = zero; acc[1] = zero;
#pragma unroll
      for (int rt = 0; rt < 2; ++rt) if (rt < nrt) {
#pragma unroll
        for (int s = 0; s < 4; ++s) {
          bf16x8 a = *(const bf16x8*)(ahL + (rt * 16 + l15) * AS + s * 32 + q * 8);
          bf16x8 bb = *(const bf16x8*)(alL + (rt * 16 + l15) * AS + s * 32 + q * 8);
          acc[rt] = __builtin_amdgcn_mfma_f32_16x16x32_bf16(a, cch[s], acc[rt], 0, 0, 0);
          acc[rt] = __builtin_amdgcn_mfma_f32_16x16x32_bf16(bb, cch[s], acc[rt], 0, 0, 0);
          acc[rt] = __builtin_amdgcn_mfma_f32_16x16x32_bf16(a, ccl[s], acc[rt], 0, 0, 0);
        }
      }
#pragma unroll
      for (int rt = 0; rt < 2; ++rt) if (rt < nrt) {
#pragma unroll
        for (int i = 0; i < 4; ++i) {
          int row = rt * 16 + q * 4 + i;
          if (cw < Uu) {
            float y = acc[rt][i] + bcv;
            float cv = 1.f - 2.f / (__expf(2.f * y) + 1.f);
            float u = (float)ugQ[row * Uu + cw] * (1.f / 65535.f);
            out[sbase + (size_t)(ch0 + row) * Uu + cw] = u * sv[rt][i] + (1.f - u) * cv;
          }
        }
      }
    }
    // no trailing barrier needed: next chunk's B only writes gch (readers all
    // passed the post-staging sync) and the post-B sync orders ahL reuse.
  }
}

// ---------------------------------------------------------------------------
extern "C" void kernel_launch(void* const* d_in, const int* in_sizes, int n_in,
                              void* d_out, int out_size, void* d_ws, size_t ws_size,
                              hipStream_t stream) {
  const float* inp   = (const float*)d_in[0];
  const float* stt   = (const float*)d_in[1];
  const int*   esrc  = (const int*)d_in[2];
  const int*   edst  = (const int*)d_in[3];
  const float* Wg    = (const float*)d_in[4];
  const float* att_s = (const float*)d_in[5];
  const float* att_d = (const float*)d_in[6];
  const float* gbias = (const float*)d_in[7];
  const float* b1    = (const float*)d_in[8];
  const float* Wru   = (const float*)d_in[9];
  const float* bru   = (const float*)d_in[10];
  const float* Wc    = (const float*)d_in[11];
  const float* bc    = (const float*)d_in[12];
  float* out = (float*)d_out;

  k_fused<<<Bb, 512, 0, stream>>>(stt, inp, Wg, att_s, att_d, esrc, edst,
                                  gbias, b1, Wru, bru, Wc, bc, out);
}